// Round 10
// baseline (382.187 us; speedup 1.0000x reference)
//
#include <hip/hip_runtime.h>

// ---------------------------------------------------------------------------
// MAF forward log-prob, fully fused. D=45, H=256, NB=6, L=2, K=8, M=23.
// R12: 32-ROW workgroups for 2x occupancy. R5-R11 all plateau at ~270us with
// 4 waves/SIMD, VALUBusy 57%, 43% issue-idle -> occupancy-limited latency
// bound (78 serial barrier-phases, ~8.5K cy each vs ~1.6K cy of work). Now:
// rows=32, one acc per wave (16 VGPR), LDS 81K->40.6K -> 4 WGs/CU = 32
// waves/CU (HW max, 2x). 1024 WGs all resident. Spline tasks 288 = 1/thread
// for t<288. Same pair-granularity K-prefix pipeline (3-pair-deep B
// prefetch); chunk counts/WG unchanged, 2x waves to hide the same chains.
// __launch_bounds__(512,4) pins 64 VGPR (2nd arg = min blocks/CU).
// ---------------------------------------------------------------------------

typedef __bf16 bf16;
typedef __bf16 bf16x8 __attribute__((ext_vector_type(8)));
typedef float  f32x16 __attribute__((ext_vector_type(16)));

#define TAILF  13.815510557964274f      /* -log(1e-6) */
#define TAIL2  27.631021115928548f      /* 2*TAILF */
#define CMIN   0.027631021115928548f    /* 2*TAILF*1e-3 */
#define LOGZ   41.352233994210265f      /* 0.5*45*log(2*pi) */

// ---------------- workspace layout (bytes) ----------------
#define WS_W0M   0            /* bf16 [6][8 cg][4 kt][512]   196608 */
#define WS_WHM   196608       /* bf16 [12][8 cg][16 kt][512] 1572864 */
#define WS_WFM   1769472      /* bf16 [30][7 cg][16 kt][512] 3440640 */
#define WS_BEFF  5210112      /* f32  [6][256]   6144 */
#define WS_BFP   5216256      /* f32  [30][224]  26880 */
#define WS_WCC   5243136      /* f32  [6][256]   6144 */
#define WS_BHP   5249280      /* f32  [12][256]  12288 */
#define WS_NEED  5261568

#define N_W0  (6*256*64)        /* 98304   */
#define N_WH  (6*2*256*256)     /* 786432  */
#define N_WF  (6*5*224*256)     /* 1720320 */
#define N_PREP (N_W0 + N_WH + N_WF)

// ---- sorted-degree permutation of hidden units ----
// orig degree-1 of unit k is k%44.  Sorted position s -> degree-1 s_deg(s),
// original index s_orig(s).  Degrees 0..35 have 6 copies, 36..43 have 5.
__device__ __forceinline__ int s_deg(int s) {
    return (s < 216) ? (s / 6) : (36 + (s - 216) / 5);
}
__device__ __forceinline__ int s_orig(int s) {
    int d, rk;
    if (s < 216) { d = s / 6; rk = s - d * 6; }
    else { int u = s - 216; d = 36 + u / 5; rk = u - (u / 5) * 5; }
    return d + 44 * rk;
}

// ---------------- merged prep kernel (mask + permute + cast + pack) --------
__global__ void prep_all(const float* __restrict__ W0, const float* __restrict__ b0,
                         const float* __restrict__ Wc, const float* __restrict__ bc,
                         const float* __restrict__ Wh, const float* __restrict__ Wf,
                         const float* __restrict__ bfv, const float* __restrict__ bh,
                         bf16* __restrict__ W0m, bf16* __restrict__ Whm,
                         bf16* __restrict__ Wfm,
                         float* __restrict__ beff, float* __restrict__ bfp,
                         float* __restrict__ Wcc, float* __restrict__ bhp)
{
    int idx = blockIdx.x * 256 + threadIdx.x;
    if (idx < N_W0) {
        int j = idx & 7, lane = (idx >> 3) & 63, chunk = idx >> 9;
        int kt = chunk & 3, cg = (chunk >> 2) & 7, b = chunk >> 5;
        int col = cg * 32 + (lane & 31);               // sorted hidden pos
        int k   = kt * 16 + (lane >> 5) * 8 + j;
        int o   = s_orig(col);
        float v = 0.f;
        if (k < 45 && s_deg(col) >= k)                 // m0: deg_h >= k+1
            v = W0[(b * 256 + o) * 45 + k];
        W0m[idx] = (bf16)v;
        if (k == 0) {
            beff[b * 256 + col] = b0[b * 256 + o] + bc[b * 256 + o];
            Wcc[b * 256 + col]  = Wc[b * 256 + o];
        }
    } else if (idx < N_W0 + N_WH) {
        int id = idx - N_W0;
        int j = id & 7, lane = (id >> 3) & 63, chunk = id >> 9;
        int kt = chunk & 15, cg = (chunk >> 4) & 7, bl = chunk >> 7;  // bl=b*2+l
        int col = cg * 32 + (lane & 31);
        int k   = kt * 16 + (lane >> 5) * 8 + j;
        int oc  = s_orig(col), ok = s_orig(k);
        float v = (s_deg(col) >= s_deg(k)) ? Wh[bl * 65536 + oc * 256 + ok] : 0.f;
        Whm[id] = (bf16)v;
        if (k == 0)
            bhp[bl * 256 + col] = bh[bl * 256 + oc];
    } else if (idx < N_PREP) {
        int id = idx - (N_W0 + N_WH);
        int j = id & 7, lane = (id >> 3) & 63, chunk = id >> 9;
        int kt = chunk & 15, t2 = chunk >> 4;
        int cg = t2 % 7, bg = t2 / 7;                  // bg = b*5+g
        int b  = bg / 5, g = bg - 5 * b;
        int col = cg * 32 + (lane & 31);               // 0..223 (param col)
        int k   = kt * 16 + (lane >> 5) * 8 + j;
        int ok  = s_orig(k);
        int f   = 9 * g + col / 23;
        int m   = col - (col / 23) * 23;
        bool valid = (col < 207);
        float v = 0.f;
        if (valid && (f > s_deg(k)))                   // mf strict
            v = Wf[(b * 1035 + f * 23 + m) * 256 + ok];
        Wfm[id] = (bf16)v;
        if (k == 0)
            bfp[bg * 224 + col] = valid ? bfv[b * 1035 + f * 23 + m] : 0.f;
    }
}

// ---------------- fused main kernel ----------------
// LDS (dynamic, 40592 B -> 4 blocks/CU):
#define SO_ZF    0        /* float [32][46]           5888 */
#define SO_ZB    5888     /* bf16  [32][56]           3584 */
#define SO_HIDA  9472     /* bf16  [32][264]         16896 */
#define SO_PBUF  26368    /* bf16  9 x 776 (32x24 + 8 skew) 13968 */
#define SO_COND  40336    /* float [32] */
#define SO_LD    40464    /* float [32] */
#define SMEM_BYTES 40592

#define PBF 776           /* elements per feature slab: 32*24 + 8 skew */

// Chunk-PAIR counts per wave (np = ceil(real_prefix_chunks / 2)).
// Chunks beyond each mask prefix are zero in the packed buffers, so the
// rounding-up to a pair is numerically free.
__constant__ unsigned char IN_NP[8]     = {1,1,1,1,1,1,2,2};
__constant__ unsigned char HID_NP[8]    = {2,3,3,5,6,6,8,8};
__constant__ unsigned char OUT_NP[5][7] = {
    {1,1,1,1,2,2,2},
    {2,3,3,3,3,4,4},
    {4,4,5,5,5,5,5},
    {6,6,6,6,7,7,7},
    {7,8,8,8,8,8,8}};

// Epilogue for one 32x32 accumulator (rows 0-31).
// C/D: col=lane&31, row=(r&3)+8*(r>>2)+4*(lane>>5).
// MODE 0: +bias+cond*wcol -> hidA; MODE 1: +bias, relu -> hidA;
// MODE 2: +bias -> pbuf (per-feature slab layout).
template<int MODE>
__device__ __forceinline__ void epi32(const f32x16& acc, int cg,
    const float* __restrict__ bias, const float* __restrict__ wcol,
    const float* condl, bf16* dst, int l31, int kh8)
{
    const int col = cg * 32 + l31;
    if (MODE == 2 && col >= 207) return;
    const float bv = bias[col];
    const int rb = kh8 >> 1;                // 4*(lane>>5)
    if (MODE == 2) {
        const int fl = col / 23, m = col - fl * 23;
        bf16* dp = dst + fl * PBF + m;
        #pragma unroll
        for (int r = 0; r < 16; ++r) {
            int row = (r & 3) + 8 * (r >> 2) + rb;
            dp[row * 24] = (bf16)(acc[r] + bv);
        }
    } else {
        const float wcv = (MODE == 0) ? wcol[col] : 0.f;
        #pragma unroll
        for (int r = 0; r < 16; ++r) {
            int row = (r & 3) + 8 * (r >> 2) + rb;
            float v = acc[r] + bv;
            if (MODE == 0) v += condl[row] * wcv;
            if (MODE == 1) v = fmaxf(v, 0.f);
            dst[row * 264 + col] = (bf16)v;
        }
    }
}

// GEMM: one cg per wave, rows 0-31, ONE accumulator. np = chunk PAIRS
// (wave-uniform; 0 = idle wave, barriers still uniform). Rolled pipeline,
// prefetch distance THREE pairs (6 chunks / 6KB in flight).
template<int KTFULL, int MODE>
__device__ __forceinline__ void gemm32r(
    const bf16* Asrc, const int lda,
    const bf16* __restrict__ Wp,
    const float* __restrict__ bias, const float* __restrict__ wcol,
    const float* condl, bf16* dst,
    int cg, int np,
    int lane, bool preEpiSync)
{
    const int l31 = lane & 31;
    const int kh8 = (lane >> 5) * 8;
    const bf16* Bp = Wp + (size_t)cg * (KTFULL * 512) + lane * 8;
    const bf16* Ap = Asrc + l31 * lda + kh8;

    f32x16 acc = {};
    bf16x8 rA0, rA1, rB0, rB1, rC0, rC1;

#define LB(c)  (*reinterpret_cast<const bf16x8*>(Bp + (size_t)(c) * 512))
#define LA(c)  (*reinterpret_cast<const bf16x8*>(Ap + (c) * 16))
#define CHUNK(breg, c) { \
    bf16x8 a_ = LA(c); \
    acc = __builtin_amdgcn_mfma_f32_32x32x16_bf16(a_, breg, acc, 0, 0, 0); }
#define LP(r0, r1, p) { r0 = LB(2*(p)); r1 = LB(2*(p)+1); }
#define CP(r0, r1, p) { CHUNK(r0, 2*(p)) CHUNK(r1, 2*(p)+1) }

    if (np > 0) {
        LP(rA0, rA1, 0);
        if (np > 1) LP(rB0, rB1, 1);
        if (np > 2) LP(rC0, rC1, 2);

        int p = 0;
        #pragma unroll 1
        while (p + 3 < np) {
            CP(rA0, rA1, p);
            LP(rA0, rA1, p + 3);
            CP(rB0, rB1, p + 1);
            if (p + 4 < np) LP(rB0, rB1, p + 4);
            CP(rC0, rC1, p + 2);
            if (p + 5 < np) LP(rC0, rC1, p + 5);
            p += 3;
        }
        CP(rA0, rA1, p);
        if (np - p > 1) CP(rB0, rB1, p + 1);
        if (np - p > 2) CP(rC0, rC1, p + 2);
    }

#undef LB
#undef LA
#undef CHUNK
#undef LP
#undef CP

    if (preEpiSync) __syncthreads();   // in-place layers / pbuf reader drain

    if (np > 0) epi32<MODE>(acc, cg, bias, wcol, condl, dst, l31, kh8);
    __syncthreads();
}

// RQ spline for 9 features starting at fb. 288 tasks = 9 features x 32 rows;
// threads t<288 take exactly one: fl = t>>5, r = t&31. No barrier inside —
// pbuf protected by the NEXT gemm's preEpiSync; zf/zb cells private.
__device__ __forceinline__ void do_spline9(int fb, float* zf, bf16* zb,
                                           const bf16* pbuf, int t, float& lad_acc)
{
    if (t >= 288) return;
    const int fl = t >> 5, r = t & 31;
    const bf16* pp = pbuf + fl * PBF + r * 24;
    bf16x8 q0 = *reinterpret_cast<const bf16x8*>(pp);
    bf16x8 q1 = *reinterpret_cast<const bf16x8*>(pp + 8);
    bf16x8 q2 = *reinterpret_cast<const bf16x8*>(pp + 16);
    float P[23];
    #pragma unroll
    for (int m = 0; m < 8; ++m) P[m]      = (float)q0[m];
    #pragma unroll
    for (int m = 0; m < 8; ++m) P[8 + m]  = (float)q1[m];
    #pragma unroll
    for (int m = 0; m < 7; ++m) P[16 + m] = (float)q2[m];

    float xin = zf[r * 46 + fb + fl];
    float xc  = fminf(fmaxf(xin, -TAILF), TAILF);
    bool inside = (xin >= -TAILF) && (xin <= TAILF);

    float mw = P[0];
    #pragma unroll
    for (int i = 1; i < 8; ++i) mw = fmaxf(mw, P[i]);
    float ew[8], sw = 0.f;
    #pragma unroll
    for (int i = 0; i < 8; ++i) { ew[i] = __expf((P[i] - mw) * 0.0625f); sw += ew[i]; }
    float rws = TAIL2 * 0.992f / sw;
    float cw[9], wb[8];
    cw[0] = -TAILF;
    #pragma unroll
    for (int i = 0; i < 8; ++i) {
        wb[i] = fmaf(ew[i], rws, CMIN);
        cw[i + 1] = cw[i] + wb[i];
    }
    cw[8] = TAILF;
    wb[7] = TAILF - cw[7];

    float mh = P[8];
    #pragma unroll
    for (int i = 1; i < 8; ++i) mh = fmaxf(mh, P[8 + i]);
    float eh[8], sh = 0.f;
    #pragma unroll
    for (int i = 0; i < 8; ++i) { eh[i] = __expf((P[8 + i] - mh) * 0.0625f); sh += eh[i]; }
    float rhs = TAIL2 * 0.992f / sh;
    float ch[9], hb[8];
    ch[0] = -TAILF;
    #pragma unroll
    for (int i = 0; i < 8; ++i) {
        hb[i] = fmaf(eh[i], rhs, CMIN);
        ch[i + 1] = ch[i] + hb[i];
    }
    ch[8] = TAILF;
    hb[7] = TAILF - ch[7];

    float dd[9];
    dd[0] = 1.0f; dd[8] = 1.0f;
    #pragma unroll
    for (int i = 1; i < 8; ++i)
        dd[i] = 1e-3f + __logf(1.f + __expf(P[15 + i]));

    float icw = cw[0], ich = ch[0], ibw = wb[0], ibh = hb[0];
    float id0 = dd[0], id1 = dd[1];
    #pragma unroll
    for (int i = 1; i < 8; ++i) {
        bool ge = xc >= cw[i];
        icw = ge ? cw[i] : icw;  ich = ge ? ch[i] : ich;
        ibw = ge ? wb[i] : ibw;  ibh = ge ? hb[i] : ibh;
        id0 = ge ? dd[i] : id0;  id1 = ge ? dd[i + 1] : id1;
    }

    float th  = (xc - icw) / ibw;
    float th1 = th * (1.f - th);
    float dl  = ibh / ibw;
    float den = dl + (id0 + id1 - 2.f * dl) * th1;
    float yy  = ich + ibh * (dl * th * th + id0 * th1) / den;
    float num = dl * dl * (id1 * th * th + 2.f * dl * th1
                           + id0 * (1.f - th) * (1.f - th));
    float lad = __logf(num) - 2.f * __logf(den);

    if (inside) {
        zf[r * 46 + fb + fl] = yy;
        zb[r * 56 + fb + fl] = (bf16)yy;
    }
    lad_acc += inside ? lad : 0.f;
}

__global__ __launch_bounds__(512, 4) void maf_main(
    const float* __restrict__ x, const float* __restrict__ cond,
    const bf16* __restrict__ W0m, const bf16* __restrict__ Whm,
    const bf16* __restrict__ Wfm,
    const float* __restrict__ beff, const float* __restrict__ bfp,
    const float* __restrict__ Wcc, const float* __restrict__ bhp,
    float* __restrict__ out, int B)
{
    extern __shared__ char smem[];
    float* zf    = (float*)(smem + SO_ZF);
    bf16*  zb    = (bf16*)(smem + SO_ZB);
    bf16*  hidA  = (bf16*)(smem + SO_HIDA);
    bf16*  pbuf  = (bf16*)(smem + SO_PBUF);
    float* condl = (float*)(smem + SO_COND);
    float* ldl   = (float*)(smem + SO_LD);

    const int t    = threadIdx.x;
    const int r0   = blockIdx.x * 32;
    const int w    = t >> 6;
    const int lane = t & 63;
    const int wu   = __builtin_amdgcn_readfirstlane(w);

    for (int i = t; i < 32 * 11; i += 512) {
        int r = i / 11, c = i - (i / 11) * 11;
        zb[r * 56 + 45 + c] = (bf16)0.f;
    }
    if (t < 8) hidA[t] = (bf16)0.f;   // zb row31 chunk-3 hi-half overreads here
    for (int i = t; i < 32 * 45; i += 512) {
        int r = i / 45, f = i - (i / 45) * 45;
        float v = (r0 + r < B) ? x[(size_t)(r0 + r) * 45 + f] : 0.f;
        zf[r * 46 + f] = v;
        zb[r * 56 + f] = (bf16)v;
    }
    if (t < 32) {
        condl[t] = (r0 + t < B) ? cond[r0 + t] : 0.f;
        ldl[t]   = 0.f;
    }
    __syncthreads();

    float lad_acc = 0.f;

    const int inNp  = IN_NP[wu];
    const int hidNp = HID_NP[wu];
    const int oNpOk = (wu < 7);                    // wave 7 idle in output

    #pragma unroll 1
    for (int b = 0; b < 6; ++b) {
        // input MADE layer (per-cg K prefix), +cond*Wc + (b0+bc)
        gemm32r<4, 0>(zb, 56, W0m + b * 16384,
                      beff + b * 256, Wcc + b * 256, condl,
                      hidA, wu, inNp, lane, false);
        // 2 hidden layers, relu, in-place
        #pragma unroll 1
        for (int l = 0; l < 2; ++l)
            gemm32r<16, 1>(hidA, 264, Whm + (b * 2 + l) * 65536,
                           bhp + (b * 2 + l) * 256, nullptr, condl,
                           hidA, wu, hidNp, lane, true);
        // params: 5 groups x 9 features. Spline(g) runs right after gemm(g)'s
        // ending barrier; gemm(g+1)'s preEpiSync drains spline readers of pbuf
        // before its epilogue overwrites it.
        #pragma unroll 1
        for (int g = 0; g < 5; ++g) {
            gemm32r<16, 2>(hidA, 264, Wfm + (size_t)(b * 5 + g) * 57344,
                           bfp + (b * 5 + g) * 224, nullptr, condl,
                           pbuf, oNpOk ? wu : 0, oNpOk ? OUT_NP[g][wu] : 0,
                           lane, g > 0);
            do_spline9(g * 9, zf, zb, pbuf, t, lad_acc);
        }
        __syncthreads();   // zb/zf complete for next block's input gemm
    }

    atomicAdd(&ldl[t & 31], lad_acc);
    __syncthreads();

    if (t < 32 && r0 + t < B) {
        float s = 0.f;
        #pragma unroll
        for (int f = 0; f < 45; ++f) { float v = zf[t * 46 + f]; s += v * v; }
        out[r0 + t] = -0.5f * s - LOGZ + ldl[t];
    }
}

// ---------------- host entry ----------------
extern "C" void kernel_launch(void* const* d_in, const int* in_sizes, int n_in,
                              void* d_out, int out_size, void* d_ws, size_t ws_size,
                              hipStream_t stream)
{
    const float* x    = (const float*)d_in[0];
    const float* cond = (const float*)d_in[1];
    const float* W0   = (const float*)d_in[2];
    const float* b0   = (const float*)d_in[3];
    const float* Wc   = (const float*)d_in[4];
    const float* bc   = (const float*)d_in[5];
    const float* Wh   = (const float*)d_in[6];
    const float* bh   = (const float*)d_in[7];
    const float* Wf   = (const float*)d_in[8];
    const float* bfv  = (const float*)d_in[9];
    float* out = (float*)d_out;

    const int B = in_sizes[0] / 45;
    if (ws_size < (size_t)WS_NEED) return;   // fail loudly

    char* ws = (char*)d_ws;
    bf16*  W0m  = (bf16*)(ws + WS_W0M);
    bf16*  Whm  = (bf16*)(ws + WS_WHM);
    bf16*  Wfm  = (bf16*)(ws + WS_WFM);
    float* beff = (float*)(ws + WS_BEFF);
    float* bfp  = (float*)(ws + WS_BFP);
    float* Wcc  = (float*)(ws + WS_WCC);
    float* bhp  = (float*)(ws + WS_BHP);

    prep_all<<<(N_PREP + 255) / 256, 256, 0, stream>>>(
        W0, b0, Wc, bc, Wh, Wf, bfv, bh, W0m, Whm, Wfm, beff, bfp, Wcc, bhp);

    (void)hipFuncSetAttribute((const void*)maf_main,
                              hipFuncAttributeMaxDynamicSharedMemorySize,
                              SMEM_BYTES);

    const int nwg = (B + 31) / 32;
    maf_main<<<nwg, 512, SMEM_BYTES, stream>>>(
        x, cond, W0m, Whm, Wfm, beff, bfp, Wcc, bhp, out, B);
}

// Round 11
// 356.754 us; speedup vs baseline: 1.0713x; 1.0713x over previous
//
#include <hip/hip_runtime.h>

// ---------------------------------------------------------------------------
// MAF forward log-prob, fully fused. D=45, H=256, NB=6, L=2, K=8, M=23.
// R13: 128-ROW workgroups, 4 accumulators/wave, 1 WG/CU. R12 proved less-ILP
// hurts (1-acc chains, 2x loads -> 335us); R13 pushes the other way: each
// wave's col-group covers 4 row-tiles, so each 1KB B-chunk feeds 4 indep
// MFMA chains (8 MFMA/pair-step ~= 128cy; 3-pair prefetch distance = 24 MFMA
// ~= 384cy > L2 latency -> B loads fully hidden). Machine-wide weight loads
// halve (256 WGs). LDS 161,936B -> 1 WG/CU; __launch_bounds__(512,1) lifts
// the 64-reg cap (needs ~116). Spline: 1152 tasks, 2-3 per thread.
// ---------------------------------------------------------------------------

typedef __bf16 bf16;
typedef __bf16 bf16x8 __attribute__((ext_vector_type(8)));
typedef float  f32x16 __attribute__((ext_vector_type(16)));

#define TAILF  13.815510557964274f      /* -log(1e-6) */
#define TAIL2  27.631021115928548f      /* 2*TAILF */
#define CMIN   0.027631021115928548f    /* 2*TAILF*1e-3 */
#define LOGZ   41.352233994210265f      /* 0.5*45*log(2*pi) */

// ---------------- workspace layout (bytes) ----------------
#define WS_W0M   0            /* bf16 [6][8 cg][4 kt][512]   196608 */
#define WS_WHM   196608       /* bf16 [12][8 cg][16 kt][512] 1572864 */
#define WS_WFM   1769472      /* bf16 [30][7 cg][16 kt][512] 3440640 */
#define WS_BEFF  5210112      /* f32  [6][256]   6144 */
#define WS_BFP   5216256      /* f32  [30][224]  26880 */
#define WS_WCC   5243136      /* f32  [6][256]   6144 */
#define WS_BHP   5249280      /* f32  [12][256]  12288 */
#define WS_NEED  5261568

#define N_W0  (6*256*64)        /* 98304   */
#define N_WH  (6*2*256*256)     /* 786432  */
#define N_WF  (6*5*224*256)     /* 1720320 */
#define N_PREP (N_W0 + N_WH + N_WF)

// ---- sorted-degree permutation of hidden units ----
// orig degree-1 of unit k is k%44.  Sorted position s -> degree-1 s_deg(s),
// original index s_orig(s).  Degrees 0..35 have 6 copies, 36..43 have 5.
__device__ __forceinline__ int s_deg(int s) {
    return (s < 216) ? (s / 6) : (36 + (s - 216) / 5);
}
__device__ __forceinline__ int s_orig(int s) {
    int d, rk;
    if (s < 216) { d = s / 6; rk = s - d * 6; }
    else { int u = s - 216; d = 36 + u / 5; rk = u - (u / 5) * 5; }
    return d + 44 * rk;
}

// ---------------- merged prep kernel (mask + permute + cast + pack) --------
__global__ void prep_all(const float* __restrict__ W0, const float* __restrict__ b0,
                         const float* __restrict__ Wc, const float* __restrict__ bc,
                         const float* __restrict__ Wh, const float* __restrict__ Wf,
                         const float* __restrict__ bfv, const float* __restrict__ bh,
                         bf16* __restrict__ W0m, bf16* __restrict__ Whm,
                         bf16* __restrict__ Wfm,
                         float* __restrict__ beff, float* __restrict__ bfp,
                         float* __restrict__ Wcc, float* __restrict__ bhp)
{
    int idx = blockIdx.x * 256 + threadIdx.x;
    if (idx < N_W0) {
        int j = idx & 7, lane = (idx >> 3) & 63, chunk = idx >> 9;
        int kt = chunk & 3, cg = (chunk >> 2) & 7, b = chunk >> 5;
        int col = cg * 32 + (lane & 31);               // sorted hidden pos
        int k   = kt * 16 + (lane >> 5) * 8 + j;
        int o   = s_orig(col);
        float v = 0.f;
        if (k < 45 && s_deg(col) >= k)                 // m0: deg_h >= k+1
            v = W0[(b * 256 + o) * 45 + k];
        W0m[idx] = (bf16)v;
        if (k == 0) {
            beff[b * 256 + col] = b0[b * 256 + o] + bc[b * 256 + o];
            Wcc[b * 256 + col]  = Wc[b * 256 + o];
        }
    } else if (idx < N_W0 + N_WH) {
        int id = idx - N_W0;
        int j = id & 7, lane = (id >> 3) & 63, chunk = id >> 9;
        int kt = chunk & 15, cg = (chunk >> 4) & 7, bl = chunk >> 7;  // bl=b*2+l
        int col = cg * 32 + (lane & 31);
        int k   = kt * 16 + (lane >> 5) * 8 + j;
        int oc  = s_orig(col), ok = s_orig(k);
        float v = (s_deg(col) >= s_deg(k)) ? Wh[bl * 65536 + oc * 256 + ok] : 0.f;
        Whm[id] = (bf16)v;
        if (k == 0)
            bhp[bl * 256 + col] = bh[bl * 256 + oc];
    } else if (idx < N_PREP) {
        int id = idx - (N_W0 + N_WH);
        int j = id & 7, lane = (id >> 3) & 63, chunk = id >> 9;
        int kt = chunk & 15, t2 = chunk >> 4;
        int cg = t2 % 7, bg = t2 / 7;                  // bg = b*5+g
        int b  = bg / 5, g = bg - 5 * b;
        int col = cg * 32 + (lane & 31);               // 0..223 (param col)
        int k   = kt * 16 + (lane >> 5) * 8 + j;
        int ok  = s_orig(k);
        int f   = 9 * g + col / 23;
        int m   = col - (col / 23) * 23;
        bool valid = (col < 207);
        float v = 0.f;
        if (valid && (f > s_deg(k)))                   // mf strict
            v = Wf[(b * 1035 + f * 23 + m) * 256 + ok];
        Wfm[id] = (bf16)v;
        if (k == 0)
            bfp[bg * 224 + col] = valid ? bfv[b * 1035 + f * 23 + m] : 0.f;
    }
}

// ---------------- fused main kernel ----------------
// LDS (dynamic, 161936 B -> 1 block/CU):
#define SO_ZF    0        /* float [128][46]          23552 */
#define SO_ZB    23552    /* bf16  [128][56]          14336 */
#define SO_HIDA  37888    /* bf16  [128][264]         67584 */
#define SO_PBUF  105472   /* bf16  9 x 3080 (128x24 + 8 skew) 55440 */
#define SO_COND  160912   /* float [128] */
#define SO_LD    161424   /* float [128] */
#define SMEM_BYTES 161936

#define PBF 3080          /* elements per feature slab: 128*24 + 8 skew */

// Chunk-PAIR counts per wave (np = ceil(real_prefix_chunks / 2)).
// Chunks beyond each mask prefix are zero in the packed buffers, so the
// rounding-up to a pair is numerically free.
__constant__ unsigned char IN_NP[8]     = {1,1,1,1,1,1,2,2};
__constant__ unsigned char HID_NP[8]    = {2,3,3,5,6,6,8,8};
__constant__ unsigned char OUT_NP[5][7] = {
    {1,1,1,1,2,2,2},
    {2,3,3,3,3,4,4},
    {4,4,5,5,5,5,5},
    {6,6,6,6,7,7,7},
    {7,8,8,8,8,8,8}};

// Epilogue for one 32x32 accumulator at row-tile `tile` (rows tile*32..+31).
// C/D: col=lane&31, row=(r&3)+8*(r>>2)+4*(lane>>5).
// MODE 0: +bias+cond*wcol -> hidA; MODE 1: +bias, relu -> hidA;
// MODE 2: +bias -> pbuf (per-feature slab layout).
template<int MODE>
__device__ __forceinline__ void epi32(const f32x16& acc, int cg, int tile,
    const float* __restrict__ bias, const float* __restrict__ wcol,
    const float* condl, bf16* dst, int l31, int kh8)
{
    const int col = cg * 32 + l31;
    if (MODE == 2 && col >= 207) return;
    const float bv = bias[col];
    const int rb = (kh8 >> 1) + tile * 32;   // 4*(lane>>5) + tile*32
    if (MODE == 2) {
        const int fl = col / 23, m = col - fl * 23;
        bf16* dp = dst + fl * PBF + m;
        #pragma unroll
        for (int r = 0; r < 16; ++r) {
            int row = (r & 3) + 8 * (r >> 2) + rb;
            dp[row * 24] = (bf16)(acc[r] + bv);
        }
    } else {
        const float wcv = (MODE == 0) ? wcol[col] : 0.f;
        #pragma unroll
        for (int r = 0; r < 16; ++r) {
            int row = (r & 3) + 8 * (r >> 2) + rb;
            float v = acc[r] + bv;
            if (MODE == 0) v += condl[row] * wcv;
            if (MODE == 1) v = fmaxf(v, 0.f);
            dst[row * 264 + col] = (bf16)v;
        }
    }
}

// GEMM: one cg per wave, FOUR row-tiles (rows 0-31/32-63/64-95/96-127), so
// each 1KB B-chunk feeds 4 independent MFMA chains. np = chunk PAIRS
// (wave-uniform; 0 = idle wave, barriers stay uniform). Rolled pipeline,
// prefetch distance THREE pairs (6 chunks / 6KB in flight; 24 MFMA per
// distance > L2 latency -> loads hidden).
template<int KTFULL, int MODE>
__device__ __forceinline__ void gemm128(
    const bf16* Asrc, const int lda,
    const bf16* __restrict__ Wp,
    const float* __restrict__ bias, const float* __restrict__ wcol,
    const float* condl, bf16* dst,
    int cg, int np,
    int lane, bool preEpiSync)
{
    const int l31 = lane & 31;
    const int kh8 = (lane >> 5) * 8;
    const bf16* Bp = Wp + (size_t)cg * (KTFULL * 512) + lane * 8;
    const bf16* A0 = Asrc + l31 * lda + kh8;
    const bf16* A1 = A0 + 32 * lda;
    const bf16* A2 = A0 + 64 * lda;
    const bf16* A3 = A0 + 96 * lda;

    f32x16 acc0 = {}, acc1 = {}, acc2 = {}, acc3 = {};
    bf16x8 rA0, rA1, rB0, rB1, rC0, rC1;

#define LB(c)  (*reinterpret_cast<const bf16x8*>(Bp + (size_t)(c) * 512))
#define CHUNK(breg, c) { \
    bf16x8 a0_ = *reinterpret_cast<const bf16x8*>(A0 + (c) * 16); \
    bf16x8 a1_ = *reinterpret_cast<const bf16x8*>(A1 + (c) * 16); \
    bf16x8 a2_ = *reinterpret_cast<const bf16x8*>(A2 + (c) * 16); \
    bf16x8 a3_ = *reinterpret_cast<const bf16x8*>(A3 + (c) * 16); \
    acc0 = __builtin_amdgcn_mfma_f32_32x32x16_bf16(a0_, breg, acc0, 0, 0, 0); \
    acc1 = __builtin_amdgcn_mfma_f32_32x32x16_bf16(a1_, breg, acc1, 0, 0, 0); \
    acc2 = __builtin_amdgcn_mfma_f32_32x32x16_bf16(a2_, breg, acc2, 0, 0, 0); \
    acc3 = __builtin_amdgcn_mfma_f32_32x32x16_bf16(a3_, breg, acc3, 0, 0, 0); }
#define LP(r0, r1, p) { r0 = LB(2*(p)); r1 = LB(2*(p)+1); }
#define CP(r0, r1, p) { CHUNK(r0, 2*(p)) CHUNK(r1, 2*(p)+1) }

    if (np > 0) {
        LP(rA0, rA1, 0);
        if (np > 1) LP(rB0, rB1, 1);
        if (np > 2) LP(rC0, rC1, 2);

        int p = 0;
        #pragma unroll 1
        while (p + 3 < np) {
            CP(rA0, rA1, p);
            LP(rA0, rA1, p + 3);
            CP(rB0, rB1, p + 1);
            if (p + 4 < np) LP(rB0, rB1, p + 4);
            CP(rC0, rC1, p + 2);
            if (p + 5 < np) LP(rC0, rC1, p + 5);
            p += 3;
        }
        CP(rA0, rA1, p);
        if (np - p > 1) CP(rB0, rB1, p + 1);
        if (np - p > 2) CP(rC0, rC1, p + 2);
    }

#undef LB
#undef CHUNK
#undef LP
#undef CP

    if (preEpiSync) __syncthreads();   // in-place layers / pbuf reader drain

    if (np > 0) {
        epi32<MODE>(acc0, cg, 0, bias, wcol, condl, dst, l31, kh8);
        epi32<MODE>(acc1, cg, 1, bias, wcol, condl, dst, l31, kh8);
        epi32<MODE>(acc2, cg, 2, bias, wcol, condl, dst, l31, kh8);
        epi32<MODE>(acc3, cg, 3, bias, wcol, condl, dst, l31, kh8);
    }
    __syncthreads();
}

// RQ spline for 9 features starting at fb. 1152 tasks = 9 features x 128
// rows; task -> (fl = task>>7, r = task&127). No barrier inside — pbuf is
// protected by the NEXT gemm's preEpiSync; zf/zb cells are task-private.
__device__ __forceinline__ void do_spline9(int fb, float* zf, bf16* zb,
                                           const bf16* pbuf, int t, float& lad_acc)
{
    #pragma unroll 1
    for (int task = t; task < 1152; task += 512) {
        int fl = task >> 7, r = task & 127;
        const bf16* pp = pbuf + fl * PBF + r * 24;
        bf16x8 q0 = *reinterpret_cast<const bf16x8*>(pp);
        bf16x8 q1 = *reinterpret_cast<const bf16x8*>(pp + 8);
        bf16x8 q2 = *reinterpret_cast<const bf16x8*>(pp + 16);
        float P[23];
        #pragma unroll
        for (int m = 0; m < 8; ++m) P[m]      = (float)q0[m];
        #pragma unroll
        for (int m = 0; m < 8; ++m) P[8 + m]  = (float)q1[m];
        #pragma unroll
        for (int m = 0; m < 7; ++m) P[16 + m] = (float)q2[m];

        float xin = zf[r * 46 + fb + fl];
        float xc  = fminf(fmaxf(xin, -TAILF), TAILF);
        bool inside = (xin >= -TAILF) && (xin <= TAILF);

        float mw = P[0];
        #pragma unroll
        for (int i = 1; i < 8; ++i) mw = fmaxf(mw, P[i]);
        float ew[8], sw = 0.f;
        #pragma unroll
        for (int i = 0; i < 8; ++i) { ew[i] = __expf((P[i] - mw) * 0.0625f); sw += ew[i]; }
        float rws = TAIL2 * 0.992f / sw;
        float cw[9], wb[8];
        cw[0] = -TAILF;
        #pragma unroll
        for (int i = 0; i < 8; ++i) {
            wb[i] = fmaf(ew[i], rws, CMIN);
            cw[i + 1] = cw[i] + wb[i];
        }
        cw[8] = TAILF;
        wb[7] = TAILF - cw[7];

        float mh = P[8];
        #pragma unroll
        for (int i = 1; i < 8; ++i) mh = fmaxf(mh, P[8 + i]);
        float eh[8], sh = 0.f;
        #pragma unroll
        for (int i = 0; i < 8; ++i) { eh[i] = __expf((P[8 + i] - mh) * 0.0625f); sh += eh[i]; }
        float rhs = TAIL2 * 0.992f / sh;
        float ch[9], hb[8];
        ch[0] = -TAILF;
        #pragma unroll
        for (int i = 0; i < 8; ++i) {
            hb[i] = fmaf(eh[i], rhs, CMIN);
            ch[i + 1] = ch[i] + hb[i];
        }
        ch[8] = TAILF;
        hb[7] = TAILF - ch[7];

        float dd[9];
        dd[0] = 1.0f; dd[8] = 1.0f;
        #pragma unroll
        for (int i = 1; i < 8; ++i)
            dd[i] = 1e-3f + __logf(1.f + __expf(P[15 + i]));

        float icw = cw[0], ich = ch[0], ibw = wb[0], ibh = hb[0];
        float id0 = dd[0], id1 = dd[1];
        #pragma unroll
        for (int i = 1; i < 8; ++i) {
            bool ge = xc >= cw[i];
            icw = ge ? cw[i] : icw;  ich = ge ? ch[i] : ich;
            ibw = ge ? wb[i] : ibw;  ibh = ge ? hb[i] : ibh;
            id0 = ge ? dd[i] : id0;  id1 = ge ? dd[i + 1] : id1;
        }

        float th  = (xc - icw) / ibw;
        float th1 = th * (1.f - th);
        float dl  = ibh / ibw;
        float den = dl + (id0 + id1 - 2.f * dl) * th1;
        float yy  = ich + ibh * (dl * th * th + id0 * th1) / den;
        float num = dl * dl * (id1 * th * th + 2.f * dl * th1
                               + id0 * (1.f - th) * (1.f - th));
        float lad = __logf(num) - 2.f * __logf(den);

        if (inside) {
            zf[r * 46 + fb + fl] = yy;
            zb[r * 56 + fb + fl] = (bf16)yy;
        }
        lad_acc += inside ? lad : 0.f;
    }
}

__global__ __launch_bounds__(512, 1) void maf_main(
    const float* __restrict__ x, const float* __restrict__ cond,
    const bf16* __restrict__ W0m, const bf16* __restrict__ Whm,
    const bf16* __restrict__ Wfm,
    const float* __restrict__ beff, const float* __restrict__ bfp,
    const float* __restrict__ Wcc, const float* __restrict__ bhp,
    float* __restrict__ out, int B)
{
    extern __shared__ char smem[];
    float* zf    = (float*)(smem + SO_ZF);
    bf16*  zb    = (bf16*)(smem + SO_ZB);
    bf16*  hidA  = (bf16*)(smem + SO_HIDA);
    bf16*  pbuf  = (bf16*)(smem + SO_PBUF);
    float* condl = (float*)(smem + SO_COND);
    float* ldl   = (float*)(smem + SO_LD);

    const int t    = threadIdx.x;
    const int r0   = blockIdx.x * 128;
    const int w    = t >> 6;
    const int lane = t & 63;
    const int wu   = __builtin_amdgcn_readfirstlane(w);

    for (int i = t; i < 128 * 11; i += 512) {
        int r = i / 11, c = i - (i / 11) * 11;
        zb[r * 56 + 45 + c] = (bf16)0.f;
    }
    if (t < 8) hidA[t] = (bf16)0.f;   // zb row127 chunk-3 hi-half overreads here
    for (int i = t; i < 128 * 45; i += 512) {
        int r = i / 45, f = i - (i / 45) * 45;
        float v = (r0 + r < B) ? x[(size_t)(r0 + r) * 45 + f] : 0.f;
        zf[r * 46 + f] = v;
        zb[r * 56 + f] = (bf16)v;
    }
    if (t < 128) {
        condl[t] = (r0 + t < B) ? cond[r0 + t] : 0.f;
        ldl[t]   = 0.f;
    }
    __syncthreads();

    float lad_acc = 0.f;

    const int inNp  = IN_NP[wu];
    const int hidNp = HID_NP[wu];
    const int oNpOk = (wu < 7);                    // wave 7 idle in output

    #pragma unroll 1
    for (int b = 0; b < 6; ++b) {
        // input MADE layer (per-cg K prefix), +cond*Wc + (b0+bc)
        gemm128<4, 0>(zb, 56, W0m + b * 16384,
                      beff + b * 256, Wcc + b * 256, condl,
                      hidA, wu, inNp, lane, false);
        // 2 hidden layers, relu, in-place
        #pragma unroll 1
        for (int l = 0; l < 2; ++l)
            gemm128<16, 1>(hidA, 264, Whm + (b * 2 + l) * 65536,
                           bhp + (b * 2 + l) * 256, nullptr, condl,
                           hidA, wu, hidNp, lane, true);
        // params: 5 groups x 9 features. Spline(g) runs right after gemm(g)'s
        // ending barrier; gemm(g+1)'s preEpiSync drains spline readers of pbuf
        // before its epilogue overwrites it.
        #pragma unroll 1
        for (int g = 0; g < 5; ++g) {
            gemm128<16, 2>(hidA, 264, Wfm + (size_t)(b * 5 + g) * 57344,
                           bfp + (b * 5 + g) * 224, nullptr, condl,
                           pbuf, oNpOk ? wu : 0, oNpOk ? OUT_NP[g][wu] : 0,
                           lane, g > 0);
            do_spline9(g * 9, zf, zb, pbuf, t, lad_acc);
        }
        __syncthreads();   // zb/zf + pbuf readers complete for next block
    }

    atomicAdd(&ldl[t & 127], lad_acc);
    __syncthreads();

    if (t < 128 && r0 + t < B) {
        float s = 0.f;
        #pragma unroll
        for (int f = 0; f < 45; ++f) { float v = zf[t * 46 + f]; s += v * v; }
        out[r0 + t] = -0.5f * s - LOGZ + ldl[t];
    }
}

// ---------------- host entry ----------------
extern "C" void kernel_launch(void* const* d_in, const int* in_sizes, int n_in,
                              void* d_out, int out_size, void* d_ws, size_t ws_size,
                              hipStream_t stream)
{
    const float* x    = (const float*)d_in[0];
    const float* cond = (const float*)d_in[1];
    const float* W0   = (const float*)d_in[2];
    const float* b0   = (const float*)d_in[3];
    const float* Wc   = (const float*)d_in[4];
    const float* bc   = (const float*)d_in[5];
    const float* Wh   = (const float*)d_in[6];
    const float* bh   = (const float*)d_in[7];
    const float* Wf   = (const float*)d_in[8];
    const float* bfv  = (const float*)d_in[9];
    float* out = (float*)d_out;

    const int B = in_sizes[0] / 45;
    if (ws_size < (size_t)WS_NEED) return;   // fail loudly

    char* ws = (char*)d_ws;
    bf16*  W0m  = (bf16*)(ws + WS_W0M);
    bf16*  Whm  = (bf16*)(ws + WS_WHM);
    bf16*  Wfm  = (bf16*)(ws + WS_WFM);
    float* beff = (float*)(ws + WS_BEFF);
    float* bfp  = (float*)(ws + WS_BFP);
    float* Wcc  = (float*)(ws + WS_WCC);
    float* bhp  = (float*)(ws + WS_BHP);

    prep_all<<<(N_PREP + 255) / 256, 256, 0, stream>>>(
        W0, b0, Wc, bc, Wh, Wf, bfv, bh, W0m, Whm, Wfm, beff, bfp, Wcc, bhp);

    (void)hipFuncSetAttribute((const void*)maf_main,
                              hipFuncAttributeMaxDynamicSharedMemorySize,
                              SMEM_BYTES);

    const int nwg = (B + 127) / 128;
    maf_main<<<nwg, 512, SMEM_BYTES, stream>>>(
        x, cond, W0m, Whm, Wfm, beff, bfp, Wcc, bhp, out, B);
}